// Round 16
// baseline (313.054 us; speedup 1.0000x reference)
//
#include <hip/hip_runtime.h>
#include <math.h>

#define B_N 32768
#define IN_DIM 1024
#define HID 64
#define D_DIM 512
#define P_N 2048

typedef __attribute__((ext_vector_type(8))) short s16x8;
typedef __attribute__((ext_vector_type(4))) float f32x4;
typedef __attribute__((ext_vector_type(16))) unsigned char u8x16;

#define LOG2E 1.44269504088896340736f
#define LN2   0.69314718055994530942f

__device__ __forceinline__ unsigned short f2bf(float f) {
    unsigned u = __float_as_uint(f);
    return (unsigned short)((u + 0x7fffu + ((u >> 16) & 1u)) >> 16);
}
__device__ __forceinline__ float bf2f(unsigned short v) {
    return __uint_as_float(((unsigned)v) << 16);
}

// async global->LDS, 16B per lane; lds dest = wave-uniform base + lane*16
__device__ __forceinline__ void gl_lds(const void* gsrc, void* ldst) {
    __builtin_amdgcn_global_load_lds(
        (const __attribute__((address_space(1))) unsigned int*)gsrc,
        (__attribute__((address_space(3))) unsigned int*)ldst, 16, 0, 0);
}

__device__ __forceinline__ s16x8 pack8(const float* s) {
    float4 x = *(const float4*)s;
    float4 y = *(const float4*)(s + 4);
    s16x8 o;
    o[0] = (short)f2bf(x.x); o[1] = (short)f2bf(x.y);
    o[2] = (short)f2bf(x.z); o[3] = (short)f2bf(x.w);
    o[4] = (short)f2bf(y.x); o[5] = (short)f2bf(y.y);
    o[6] = (short)f2bf(y.z); o[7] = (short)f2bf(y.w);
    return o;
}

// ---------------------------------------------------------------------------
// k_prep: ALL weight/proto packing + pnorm in ONE dispatch.
// ---------------------------------------------------------------------------
__global__ __launch_bounds__(256) void k_prep(const float* __restrict__ protos,
                                              const float* __restrict__ Wmu,
                                              const float* __restrict__ Wvar,
                                              const float* __restrict__ W0,
                                              const float* __restrict__ W1,
                                              unsigned short* __restrict__ pb16,
                                              float* __restrict__ pnorm,
                                              unsigned short* __restrict__ wmv16,
                                              unsigned short* __restrict__ w0pack,
                                              unsigned short* __restrict__ w1pack) {
    int gid = blockIdx.x * 256 + threadIdx.x;
    if (gid < 131072) {
        int row = gid >> 6, k8 = gid & 63;
        const float* s = protos + (size_t)row * 512 + k8 * 8;
        float4 x = *(const float4*)s;
        float4 y = *(const float4*)(s + 4);
        s16x8 o;
        o[0] = (short)f2bf(x.x); o[1] = (short)f2bf(x.y);
        o[2] = (short)f2bf(x.z); o[3] = (short)f2bf(x.w);
        o[4] = (short)f2bf(y.x); o[5] = (short)f2bf(y.y);
        o[6] = (short)f2bf(y.z); o[7] = (short)f2bf(y.w);
        ((s16x8*)pb16)[(size_t)row * 64 + k8] = o;
        float ss = x.x * x.x + x.y * x.y + x.z * x.z + x.w * x.w +
                   y.x * y.x + y.y * y.y + y.z * y.z + y.w * y.w;
#pragma unroll
        for (int d = 1; d < 64; d <<= 1) ss += __shfl_xor(ss, d);
        if ((threadIdx.x & 63) == 0) pnorm[row] = ss;
    } else if (gid < 196608) {
        int a = gid - 131072;
        int row = a >> 6, k8 = a & 63;
        int g = row >> 5, i = row & 31;
        const float* s = (i < 16 ? Wmu + (size_t)(g * 16 + i) * 512
                                 : Wvar + (size_t)(g * 16 + i - 16) * 512) + k8 * 8;
        ((s16x8*)wmv16)[(size_t)row * 64 + k8] = pack8(s);
    } else if (gid < 204800) {
        int a = gid - 196608;          // nrows=64, nk8=128, nk32=32
        int row = a >> 7, k8 = a & 127;
        int K32 = k8 >> 2;
        int lane = (row & 15) | ((k8 & 3) << 4);
        ((s16x8*)w0pack)[((size_t)(row >> 4) * 32 + K32) * 64 + lane] =
            pack8(W0 + (size_t)row * IN_DIM + k8 * 8);
    } else {
        int a = gid - 204800;          // nrows=512, nk8=8, nk32=2
        int row = a >> 3, k8 = a & 7;
        int K32 = k8 >> 2;
        int lane = (row & 15) | ((k8 & 3) << 4);
        ((s16x8*)w1pack)[((size_t)(row >> 4) * 2 + K32) * 64 + lane] =
            pack8(W1 + (size_t)row * HID + k8 * 8);
    }
}

// ---------------------------------------------------------------------------
// K1 (fused encoder): h2 = relu(relu(x@W0^T+b0)@W1^T+b1), [B,1024]->[B,512].
// ---------------------------------------------------------------------------
__global__ __launch_bounds__(256, 4) void k_enc(const float* __restrict__ x,
                                                const unsigned short* __restrict__ w0p,
                                                const float* __restrict__ b0,
                                                const unsigned short* __restrict__ w1p,
                                                const float* __restrict__ b1,
                                                unsigned short* __restrict__ h2b) {
    __shared__ s16x8 As[1024];  // 64 rows x 128 bf16 staging (16 KB); reused for h1 tile
    const int tid = threadIdx.x;
    const int l = tid & 63, wid = tid >> 6;
    const int bm = blockIdx.x * 64;
    const s16x8* w0p8 = (const s16x8*)w0p;
    const s16x8* w1p8 = (const s16x8*)w1p;

    const int srow = tid >> 2, ssub = tid & 3;
    const int srb = srow * 256, ssw = (srow & 7) << 4;
    const int klane = (l >> 4) << 4;
    const int sw = (l & 7) << 4;
    const int arow = wid * 16 + (l & 15);

    // ---------------- phase 1: h1 = relu(x @ W0^T + b0) ----------------
    f32x4 acc1[4];
#pragma unroll
    for (int pf = 0; pf < 4; ++pf) acc1[pf] = (f32x4)0.f;

    for (int kt = 0; kt < 8; ++kt) {
        const float* src = x + (size_t)(bm + srow) * IN_DIM + kt * 128 + ssub * 32;
#pragma unroll
        for (int it = 0; it < 4; ++it) {
            s16x8 o = pack8(src + it * 8);
            int kbyte = ssub * 64 + it * 16;
            As[(srb + (kbyte ^ ssw)) >> 4] = o;
        }
        __syncthreads();
#pragma unroll
        for (int K32 = 0; K32 < 4; ++K32) {
            const int Kg = kt * 4 + K32;
            s16x8 b[4];
#pragma unroll
            for (int pf = 0; pf < 4; ++pf) b[pf] = w0p8[((size_t)pf * 32 + Kg) * 64 + l];
            s16x8 a = As[(arow * 256 + ((K32 * 64 + klane) ^ sw)) >> 4];
#pragma unroll
            for (int pf = 0; pf < 4; ++pf)
                acc1[pf] = __builtin_amdgcn_mfma_f32_16x16x32_bf16(a, b[pf], acc1[pf], 0, 0, 0);
        }
        __syncthreads();
    }

    {
        unsigned short* Hs = (unsigned short*)As;
#pragma unroll
        for (int pf = 0; pf < 4; ++pf) {
            const int c = pf * 16 + (l & 15);
            const float bb = b0[c];
#pragma unroll
            for (int j = 0; j < 4; ++j) {
                const int r = wid * 16 + (l >> 4) * 4 + j;
                float v = fmaxf(acc1[pf][j] + bb, 0.f);
                int byte = r * 128 + ((c * 2) ^ ((r & 7) << 4));
                Hs[byte >> 1] = f2bf(v);
            }
        }
    }
    __syncthreads();

    // ---------------- phase 2: h2 = relu(h1 @ W1^T + b1) ----------------
    s16x8 a2[2];
#pragma unroll
    for (int K32 = 0; K32 < 2; ++K32)
        a2[K32] = As[(arow * 128 + ((K32 * 64 + klane) ^ sw)) >> 4];

    const int r0 = bm + wid * 16 + (l >> 4) * 4;
#pragma unroll
    for (int ct = 0; ct < 4; ++ct) {
        f32x4 acc2[8];
#pragma unroll
        for (int pf = 0; pf < 8; ++pf) acc2[pf] = (f32x4)0.f;
#pragma unroll
        for (int K32 = 0; K32 < 2; ++K32)
#pragma unroll
            for (int pf = 0; pf < 8; ++pf) {
                s16x8 b = w1p8[(((size_t)(ct * 8 + pf)) * 2 + K32) * 64 + l];
                acc2[pf] = __builtin_amdgcn_mfma_f32_16x16x32_bf16(a2[K32], b, acc2[pf], 0, 0, 0);
            }
#pragma unroll
        for (int pf = 0; pf < 8; ++pf) {
            const int c = ct * 128 + pf * 16 + (l & 15);
            const float bb = b1[c];
#pragma unroll
            for (int j = 0; j < 4; ++j)
                h2b[(size_t)(r0 + j) * D_DIM + c] = f2bf(fmaxf(acc2[pf][j] + bb, 0.f));
        }
    }
}

// ===========================================================================
// m97-style GEMM core + T2 source-swizzle (2D grid, x=bm y=bn).
// ===========================================================================
#define GEMM_CORE(Aptr, Bptr)                                                  \
    __shared__ s16x8 A8[1024];                                                 \
    __shared__ s16x8 B8[1024];                                                 \
    const int tid = threadIdx.x;                                               \
    const int l = tid & 63, w = tid >> 6;                                      \
    const int bm = blockIdx.x * 128;                                           \
    const int bn = blockIdx.y * 128;                                           \
    const int wr = w >> 1, wc = w & 1;                                         \
    const int srow = l >> 3;                                                   \
    const int scol = (((l & 7) ^ ((l >> 3) & 7)) * 8);                         \
    f32x4 acc[4][4];                                                           \
    _Pragma("unroll") for (int m = 0; m < 4; ++m)                              \
        _Pragma("unroll") for (int n = 0; n < 4; ++n) acc[m][n] = (f32x4)0.f;  \
    for (int kt = 0; kt < 8; ++kt) {                                           \
        __syncthreads();                                                       \
        _Pragma("unroll") for (int i = 0; i < 4; ++i) {                        \
            const int rb = w * 32 + i * 8;                                     \
            gl_lds(Aptr + (size_t)(bm + rb + srow) * 512 + kt * 64 + scol,     \
                   (char*)A8 + rb * 128);                                      \
            gl_lds(Bptr + (size_t)(bn + rb + srow) * 512 + kt * 64 + scol,     \
                   (char*)B8 + rb * 128);                                      \
        }                                                                      \
        __syncthreads();                                                       \
        _Pragma("unroll") for (int K32 = 0; K32 < 2; ++K32) {                  \
            const int kb = (K32 * 64 + (l >> 4) * 16) ^ ((l & 7) << 4);        \
            s16x8 a[4], b[4];                                                  \
            _Pragma("unroll") for (int m = 0; m < 4; ++m)                      \
                a[m] = A8[((wr * 64 + m * 16 + (l & 15)) * 128 + kb) >> 4];    \
            _Pragma("unroll") for (int n = 0; n < 4; ++n)                      \
                b[n] = B8[((wc * 64 + n * 16 + (l & 15)) * 128 + kb) >> 4];    \
            _Pragma("unroll") for (int m = 0; m < 4; ++m)                      \
                _Pragma("unroll") for (int n = 0; n < 4; ++n)                  \
                    acc[m][n] = __builtin_amdgcn_mfma_f32_16x16x32_bf16(       \
                        a[m], b[n], acc[m][n], 0, 0, 0);                       \
        }                                                                      \
    }

// ---------------------------------------------------------------------------
// K3 (GEMM): mu/var + reparameterize + KL + Σ||latent||².
// exp(lv) computed as (exp(0.5lv))² — one transcendental per element.
// ---------------------------------------------------------------------------
__global__ __launch_bounds__(256, 4) void k_mv(const unsigned short* __restrict__ h2b,
                                               const unsigned short* __restrict__ wmv16,
                                               const float* __restrict__ bmu,
                                               const float* __restrict__ bvar,
                                               const float* __restrict__ eps,
                                               unsigned short* __restrict__ lat16,
                                               float* __restrict__ scal) {
    GEMM_CORE(h2b, wmv16)
    __shared__ float redK[4];
    __shared__ float redL[4];
    float kl = 0.f, ln = 0.f;
    const int dbase0 = (bn >> 1) + wc * 32;
#pragma unroll
    for (int m = 0; m < 4; ++m)
#pragma unroll
        for (int nn = 0; nn < 2; ++nn) {
            const int d = dbase0 + nn * 16 + (l & 15);
            const float bmv = bmu[d], bvv = bvar[d];
#pragma unroll
            for (int j = 0; j < 4; ++j) {
                const int r = bm + wr * 64 + m * 16 + (l >> 4) * 4 + j;
                float mu = acc[m][2 * nn][j] + bmv;
                float lv = acc[m][2 * nn + 1][j] + bvv;
                float eh = __expf(0.5f * lv);
                float ev = __builtin_nontemporal_load(&eps[(size_t)r * D_DIM + d]);
                float la = fmaf(ev, eh, mu);
                lat16[(size_t)r * D_DIM + d] = f2bf(la);
                kl += mu * mu + eh * eh - lv - 1.f;
                ln += la * la;
            }
        }
    kl *= 0.5f;
#pragma unroll
    for (int d = 1; d < 64; d <<= 1) {
        kl += __shfl_xor(kl, d);
        ln += __shfl_xor(ln, d);
    }
    if (l == 0) { redK[w] = kl; redL[w] = ln; }
    __syncthreads();
    if (tid == 0) {
        atomicAdd(&scal[0], redK[0] + redK[1] + redK[2] + redK[3]);
        atomicAdd(&scal[1], redL[0] + redL[1] + redL[2] + redL[3]);
    }
}

// ---------------------------------------------------------------------------
// K4 (GEMM sweep0): per-row sumexp + packed-key argmax (base-2 domain:
// gv2 = g*log2e, e = exp2(gv2) — native v_exp, no per-exp mul), exp stored
// as u8 fixed-point (e = 0.01*q + 0.1) via NT stores.
// ---------------------------------------------------------------------------
__global__ __launch_bounds__(256, 4) void k_vq1(const unsigned short* __restrict__ lat16,
                                                const unsigned short* __restrict__ pb16,
                                                const float* __restrict__ pnorm,
                                                float* __restrict__ rowS,
                                                unsigned* __restrict__ rowKey,
                                                unsigned char* __restrict__ gA,
                                                unsigned char* __restrict__ gB) {
    GEMM_CORE(lat16, pb16)
    __shared__ float rowS_l[128];
    __shared__ unsigned rowKey_l[128];
    if (tid < 128) { rowS_l[tid] = 0.f; rowKey_l[tid] = 0u; }
    __syncthreads();
    float pnl[4];
#pragma unroll
    for (int n = 0; n < 4; ++n) pnl[n] = pnorm[bn + wc * 64 + n * 16 + (l & 15)] * LOG2E;
    u8x16* gd16 = (u8x16*)((blockIdx.y < 8) ? gA : gB);
    const size_t gbase = ((size_t)((blockIdx.y & 7) * 256 + blockIdx.x) * 4) * 256;
#pragma unroll
    for (int m = 0; m < 4; ++m) {
        float gv[4][4], ev[4][4];
#pragma unroll
        for (int n = 0; n < 4; ++n)
#pragma unroll
            for (int j = 0; j < 4; ++j) {
                gv[n][j] = fmaf(acc[m][n][j], 2.f * LOG2E, -pnl[n]);
                ev[n][j] = exp2f(gv[n][j]);
            }
        u8x16 u;
#pragma unroll
        for (int n = 0; n < 4; ++n)
#pragma unroll
            for (int j = 0; j < 4; ++j) {
                float q = fmaf(ev[n][j], 100.f, -10.f);
                q = fminf(fmaxf(q, 0.f), 255.f);
                u[n * 4 + j] = (unsigned char)(q + 0.5f);
            }
        __builtin_nontemporal_store(u, &gd16[gbase + (size_t)m * 256 + tid]);
#pragma unroll
        for (int j = 0; j < 4; ++j) {
            float se = ev[0][j] + ev[1][j] + ev[2][j] + ev[3][j];
            unsigned key = 0u;
#pragma unroll
            for (int n = 0; n < 4; ++n) {
                const int p = bn + wc * 64 + n * 16 + (l & 15);
                unsigned kk = (__float_as_uint(gv[n][j] + 16.0f) & 0xFFFFF800u) | (unsigned)(2047 - p);
                key = key > kk ? key : kk;
            }
#pragma unroll
            for (int d = 1; d < 16; d <<= 1) {
                se += __shfl_xor(se, d);
                unsigned ok = (unsigned)__shfl_xor((int)key, d);
                key = key > ok ? key : ok;
            }
            if ((l & 15) == 0) {
                const int rloc = wr * 64 + m * 16 + (l >> 4) * 4 + j;
                atomicAdd(&rowS_l[rloc], se);
                atomicMax(&rowKey_l[rloc], key);
            }
        }
    }
    __syncthreads();
    if (tid < 128) {
        atomicAdd(&rowS[bm + tid], rowS_l[tid]);
        atomicMax(&rowKey[bm + tid], rowKey_l[tid]);
    }
}

// ---------------------------------------------------------------------------
// K5 (streaming + fused gather): soft_acc[p] += Σ_rows e/rowS, e=0.01q+0.1;
// plus each block gathers 8 quantized rows into `out` (NT stores).
// ---------------------------------------------------------------------------
__global__ __launch_bounds__(256, 4) void k_vq2s(const unsigned char* __restrict__ gA,
                                                 const unsigned char* __restrict__ gB,
                                                 const float* __restrict__ rowS,
                                                 const unsigned* __restrict__ rowKey,
                                                 const float* __restrict__ protos,
                                                 float* __restrict__ out,
                                                 float* __restrict__ soft_acc) {
    __shared__ float soft_l[128];
    const int tid = threadIdx.x;
    const int l = tid & 63, w = tid >> 6;
    const int wr = w >> 1, wc = w & 1;
    const int bm = blockIdx.x * 128;
    const int bn = blockIdx.y * 128;
    if (tid < 128) soft_l[tid] = 0.f;
    __syncthreads();

    const u8x16* gs16 = (const u8x16*)((blockIdx.y < 8) ? gA : gB);
    const size_t gbase = ((size_t)((blockIdx.y & 7) * 256 + blockIdx.x) * 4) * 256;

    float is[4][4];
    float isum = 0.f;
#pragma unroll
    for (int m = 0; m < 4; ++m)
#pragma unroll
        for (int j = 0; j < 4; ++j) {
            is[m][j] = 1.0f / rowS[bm + wr * 64 + m * 16 + (l >> 4) * 4 + j];
            isum += is[m][j];
        }

    float qs[4] = {0.f, 0.f, 0.f, 0.f};
#pragma unroll
    for (int m = 0; m < 4; ++m) {
        u8x16 u = __builtin_nontemporal_load(&gs16[gbase + (size_t)m * 256 + tid]);
#pragma unroll
        for (int n = 0; n < 4; ++n)
#pragma unroll
            for (int j = 0; j < 4; ++j)
                qs[n] += (float)u[n * 4 + j] * is[m][j];
    }
    float cs[4];
#pragma unroll
    for (int n = 0; n < 4; ++n) cs[n] = fmaf(0.01f, qs[n], 0.1f * isum);
#pragma unroll
    for (int n = 0; n < 4; ++n) {
        cs[n] += __shfl_xor(cs[n], 16);
        cs[n] += __shfl_xor(cs[n], 32);
    }
    if (l < 16) {
#pragma unroll
        for (int n = 0; n < 4; ++n) atomicAdd(&soft_l[wc * 64 + n * 16 + l], cs[n]);
    }
    __syncthreads();
    if (tid < 128) atomicAdd(&soft_acc[bn + tid], soft_l[tid]);

    // fused gather: this block's 8 rows of quantized output
    {
        const int row = bm + blockIdx.y * 8 + (tid >> 5);
        const int p = 2047 - (int)(rowKey[row] & 2047u);
        const f32x4* qp = (const f32x4*)(protos + (size_t)p * D_DIM);
        f32x4* op = (f32x4*)(out + (size_t)row * D_DIM);
#pragma unroll
        for (int i = 0; i < 4; ++i) {
            f32x4 q = qp[(tid & 31) + i * 32];
            __builtin_nontemporal_store(q, &op[(tid & 31) + i * 32]);
        }
    }
}

// ---------------------------------------------------------------------------
// K6: finalize scalars. vq = (Σ||l||² − ln2·Σ gv2_max) / (B·D).
// ---------------------------------------------------------------------------
__global__ __launch_bounds__(256) void k_final(const float* __restrict__ soft_acc,
                                               const float* __restrict__ scal,
                                               const unsigned* __restrict__ rowKey,
                                               float* __restrict__ out) {
    const int tid = threadIdx.x;
    __shared__ float red[256];
    float vals[8];
    float s = 0.f;
#pragma unroll
    for (int i = 0; i < 8; ++i) {
        float v = soft_acc[tid * 8 + i] * (1.0f / B_N) + 1e-6f;
        vals[i] = v;
        s += v;
    }
    red[tid] = s;
    __syncthreads();
    for (int off = 128; off > 0; off >>= 1) {
        if (tid < off) red[tid] += red[tid + off];
        __syncthreads();
    }
    float norm = red[0];
    __syncthreads();
    float e = 0.f;
#pragma unroll
    for (int i = 0; i < 8; ++i) {
        float p = vals[i] / norm;
        e -= p * __logf(p);
    }
    red[tid] = e;
    __syncthreads();
    for (int off = 128; off > 0; off >>= 1) {
        if (tid < off) red[tid] += red[tid + off];
        __syncthreads();
    }
    float ent = red[0];
    __syncthreads();
    float gsum = 0.f;
    for (int i = 0; i < 128; ++i) {
        unsigned k = rowKey[i * 256 + tid];
        gsum += __uint_as_float(k & 0xFFFFF800u) - 16.0f;   // gv2_max (base-2)
    }
    red[tid] = gsum;
    __syncthreads();
    for (int off = 128; off > 0; off >>= 1) {
        if (tid < off) red[tid] += red[tid + off];
        __syncthreads();
    }
    if (tid == 0) {
        float div = scal[0] * (1.0f / B_N);
        float vq = (scal[1] - red[0] * LN2) * (1.0f / ((float)B_N * (float)D_DIM));
        float vq_loss = 1.25f * vq + 0.1f * ent;
        float total = 0.01f * div + vq_loss;
        out[(size_t)B_N * D_DIM] = total;
        out[(size_t)B_N * D_DIM + 1] = div;
    }
}

// ---------------------------------------------------------------------------
extern "C" void kernel_launch(void* const* d_in, const int* in_sizes, int n_in,
                              void* d_out, int out_size, void* d_ws, size_t ws_size,
                              hipStream_t stream) {
    const float* x = (const float*)d_in[0];
    const float* W0 = (const float*)d_in[1];
    const float* b0 = (const float*)d_in[2];
    const float* W1 = (const float*)d_in[3];
    const float* b1 = (const float*)d_in[4];
    const float* Wmu = (const float*)d_in[5];
    const float* bmu = (const float*)d_in[6];
    const float* Wvar = (const float*)d_in[7];
    const float* bvar = (const float*)d_in[8];
    const float* protos = (const float*)d_in[9];
    const float* eps = (const float*)d_in[10];
    float* out = (float*)d_out;

    unsigned short* wsp = (unsigned short*)d_ws;
    unsigned short* lat16 = wsp;                                 // 32MB
    unsigned short* pb16 = lat16 + (size_t)B_N * D_DIM;          // 2MB
    unsigned short* wmv16 = pb16 + (size_t)P_N * D_DIM;          // 2MB
    unsigned short* w0pack = wmv16 + (size_t)2 * D_DIM * D_DIM;  // 128KB
    unsigned short* w1pack = w0pack + (size_t)HID * IN_DIM;      // 64KB
    float* pnorm = (float*)(w1pack + (size_t)D_DIM * HID);       // 8KB
    float* rowS = pnorm + P_N;                                   // 128KB
    unsigned* rowKey = (unsigned*)(rowS + B_N);                  // 128KB
    float* soft = (float*)(rowKey + B_N);                        // 8KB
    float* scal = soft + P_N;                                    // 8B
    unsigned char* gA = (unsigned char*)(scal + 2 + 510);        // 32MB u8 (live after k_mv)
    unsigned char* gB = gA + ((size_t)16 << 20) * 2;             // 32MB u8
    unsigned short* h2b = (unsigned short*)gA + (size_t)B_N * HID; // 32MB @ gA+4MB (dead before gA/gB writes)

    hipMemsetAsync(rowS, 0, (size_t)(B_N * 2 + P_N + 2) * 4, stream);

    k_prep<<<816, 256, 0, stream>>>(protos, Wmu, Wvar, W0, W1,
                                    pb16, pnorm, wmv16, w0pack, w1pack);

    k_enc<<<B_N / 64, 256, 0, stream>>>(x, w0pack, b0, w1pack, b1, h2b);

    dim3 gmv(B_N / 128, 8);
    k_mv<<<gmv, 256, 0, stream>>>(h2b, wmv16, bmu, bvar, eps, lat16, scal);

    dim3 gvq(B_N / 128, 16);
    k_vq1<<<gvq, 256, 0, stream>>>(lat16, pb16, pnorm, rowS, rowKey, gA, gB);
    k_vq2s<<<gvq, 256, 0, stream>>>(gA, gB, rowS, rowKey, protos, out, soft);

    k_final<<<1, 256, 0, stream>>>(soft, scal, rowKey, out);
}

// Round 17
// 291.631 us; speedup vs baseline: 1.0735x; 1.0735x over previous
//
#include <hip/hip_runtime.h>
#include <math.h>

#define B_N 32768
#define IN_DIM 1024
#define HID 64
#define D_DIM 512
#define P_N 2048

typedef __attribute__((ext_vector_type(8))) short s16x8;
typedef __attribute__((ext_vector_type(4))) float f32x4;

__device__ __forceinline__ unsigned short f2bf(float f) {
    unsigned u = __float_as_uint(f);
    return (unsigned short)((u + 0x7fffu + ((u >> 16) & 1u)) >> 16);
}
__device__ __forceinline__ float bf2f(unsigned short v) {
    return __uint_as_float(((unsigned)v) << 16);
}

// async global->LDS, 16B per lane; lds dest = wave-uniform base + lane*16
__device__ __forceinline__ void gl_lds(const void* gsrc, void* ldst) {
    __builtin_amdgcn_global_load_lds(
        (const __attribute__((address_space(1))) unsigned int*)gsrc,
        (__attribute__((address_space(3))) unsigned int*)ldst, 16, 0, 0);
}

__device__ __forceinline__ s16x8 pack8(const float* s) {
    float4 x = *(const float4*)s;
    float4 y = *(const float4*)(s + 4);
    s16x8 o;
    o[0] = (short)f2bf(x.x); o[1] = (short)f2bf(x.y);
    o[2] = (short)f2bf(x.z); o[3] = (short)f2bf(x.w);
    o[4] = (short)f2bf(y.x); o[5] = (short)f2bf(y.y);
    o[6] = (short)f2bf(y.z); o[7] = (short)f2bf(y.w);
    return o;
}

// ---------------------------------------------------------------------------
// k_prep: ALL weight/proto packing + pnorm in ONE dispatch.
// ---------------------------------------------------------------------------
__global__ __launch_bounds__(256) void k_prep(const float* __restrict__ protos,
                                              const float* __restrict__ Wmu,
                                              const float* __restrict__ Wvar,
                                              const float* __restrict__ W0,
                                              const float* __restrict__ W1,
                                              unsigned short* __restrict__ pb16,
                                              float* __restrict__ pnorm,
                                              unsigned short* __restrict__ wmv16,
                                              unsigned short* __restrict__ w0pack,
                                              unsigned short* __restrict__ w1pack) {
    int gid = blockIdx.x * 256 + threadIdx.x;
    if (gid < 131072) {
        int row = gid >> 6, k8 = gid & 63;
        const float* s = protos + (size_t)row * 512 + k8 * 8;
        float4 x = *(const float4*)s;
        float4 y = *(const float4*)(s + 4);
        s16x8 o;
        o[0] = (short)f2bf(x.x); o[1] = (short)f2bf(x.y);
        o[2] = (short)f2bf(x.z); o[3] = (short)f2bf(x.w);
        o[4] = (short)f2bf(y.x); o[5] = (short)f2bf(y.y);
        o[6] = (short)f2bf(y.z); o[7] = (short)f2bf(y.w);
        ((s16x8*)pb16)[(size_t)row * 64 + k8] = o;
        float ss = x.x * x.x + x.y * x.y + x.z * x.z + x.w * x.w +
                   y.x * y.x + y.y * y.y + y.z * y.z + y.w * y.w;
#pragma unroll
        for (int d = 1; d < 64; d <<= 1) ss += __shfl_xor(ss, d);
        if ((threadIdx.x & 63) == 0) pnorm[row] = ss;
    } else if (gid < 196608) {
        int a = gid - 131072;
        int row = a >> 6, k8 = a & 63;
        int g = row >> 5, i = row & 31;
        const float* s = (i < 16 ? Wmu + (size_t)(g * 16 + i) * 512
                                 : Wvar + (size_t)(g * 16 + i - 16) * 512) + k8 * 8;
        ((s16x8*)wmv16)[(size_t)row * 64 + k8] = pack8(s);
    } else if (gid < 204800) {
        int a = gid - 196608;          // nrows=64, nk8=128, nk32=32
        int row = a >> 7, k8 = a & 127;
        int K32 = k8 >> 2;
        int lane = (row & 15) | ((k8 & 3) << 4);
        ((s16x8*)w0pack)[((size_t)(row >> 4) * 32 + K32) * 64 + lane] =
            pack8(W0 + (size_t)row * IN_DIM + k8 * 8);
    } else {
        int a = gid - 204800;          // nrows=512, nk8=8, nk32=2
        int row = a >> 3, k8 = a & 7;
        int K32 = k8 >> 2;
        int lane = (row & 15) | ((k8 & 3) << 4);
        ((s16x8*)w1pack)[((size_t)(row >> 4) * 2 + K32) * 64 + lane] =
            pack8(W1 + (size_t)row * HID + k8 * 8);
    }
}

// ---------------------------------------------------------------------------
// K1 (fused encoder): h2 = relu(relu(x@W0^T+b0)@W1^T+b1), [B,1024]->[B,512].
// BM=64, 512 blocks. Phase 1: h1 tile (64x64) -> LDS (bf16, swizzled). Phase
// 2: K=64 GEMM vs w1pack -> h2b. No h1 global round-trip.
// ---------------------------------------------------------------------------
__global__ __launch_bounds__(256, 4) void k_enc(const float* __restrict__ x,
                                                const unsigned short* __restrict__ w0p,
                                                const float* __restrict__ b0,
                                                const unsigned short* __restrict__ w1p,
                                                const float* __restrict__ b1,
                                                unsigned short* __restrict__ h2b) {
    __shared__ s16x8 As[1024];  // 64 rows x 128 bf16 staging (16 KB); reused for h1 tile
    const int tid = threadIdx.x;
    const int l = tid & 63, wid = tid >> 6;
    const int bm = blockIdx.x * 64;
    const s16x8* w0p8 = (const s16x8*)w0p;
    const s16x8* w1p8 = (const s16x8*)w1p;

    const int srow = tid >> 2, ssub = tid & 3;
    const int srb = srow * 256, ssw = (srow & 7) << 4;
    const int klane = (l >> 4) << 4;
    const int sw = (l & 7) << 4;
    const int arow = wid * 16 + (l & 15);

    // ---------------- phase 1: h1 = relu(x @ W0^T + b0) ----------------
    f32x4 acc1[4];
#pragma unroll
    for (int pf = 0; pf < 4; ++pf) acc1[pf] = (f32x4)0.f;

    for (int kt = 0; kt < 8; ++kt) {
        const float* src = x + (size_t)(bm + srow) * IN_DIM + kt * 128 + ssub * 32;
#pragma unroll
        for (int it = 0; it < 4; ++it) {
            s16x8 o = pack8(src + it * 8);
            int kbyte = ssub * 64 + it * 16;
            As[(srb + (kbyte ^ ssw)) >> 4] = o;
        }
        __syncthreads();
#pragma unroll
        for (int K32 = 0; K32 < 4; ++K32) {
            const int Kg = kt * 4 + K32;
            s16x8 b[4];
#pragma unroll
            for (int pf = 0; pf < 4; ++pf) b[pf] = w0p8[((size_t)pf * 32 + Kg) * 64 + l];
            s16x8 a = As[(arow * 256 + ((K32 * 64 + klane) ^ sw)) >> 4];
#pragma unroll
            for (int pf = 0; pf < 4; ++pf)
                acc1[pf] = __builtin_amdgcn_mfma_f32_16x16x32_bf16(a, b[pf], acc1[pf], 0, 0, 0);
        }
        __syncthreads();
    }

    {
        unsigned short* Hs = (unsigned short*)As;
#pragma unroll
        for (int pf = 0; pf < 4; ++pf) {
            const int c = pf * 16 + (l & 15);
            const float bb = b0[c];
#pragma unroll
            for (int j = 0; j < 4; ++j) {
                const int r = wid * 16 + (l >> 4) * 4 + j;
                float v = fmaxf(acc1[pf][j] + bb, 0.f);
                int byte = r * 128 + ((c * 2) ^ ((r & 7) << 4));
                Hs[byte >> 1] = f2bf(v);
            }
        }
    }
    __syncthreads();

    // ---------------- phase 2: h2 = relu(h1 @ W1^T + b1) ----------------
    s16x8 a2[2];
#pragma unroll
    for (int K32 = 0; K32 < 2; ++K32)
        a2[K32] = As[(arow * 128 + ((K32 * 64 + klane) ^ sw)) >> 4];

    const int r0 = bm + wid * 16 + (l >> 4) * 4;
#pragma unroll
    for (int ct = 0; ct < 4; ++ct) {
        f32x4 acc2[8];
#pragma unroll
        for (int pf = 0; pf < 8; ++pf) acc2[pf] = (f32x4)0.f;
#pragma unroll
        for (int K32 = 0; K32 < 2; ++K32)
#pragma unroll
            for (int pf = 0; pf < 8; ++pf) {
                s16x8 b = w1p8[(((size_t)(ct * 8 + pf)) * 2 + K32) * 64 + l];
                acc2[pf] = __builtin_amdgcn_mfma_f32_16x16x32_bf16(a2[K32], b, acc2[pf], 0, 0, 0);
            }
#pragma unroll
        for (int pf = 0; pf < 8; ++pf) {
            const int c = ct * 128 + pf * 16 + (l & 15);
            const float bb = b1[c];
#pragma unroll
            for (int j = 0; j < 4; ++j)
                h2b[(size_t)(r0 + j) * D_DIM + c] = f2bf(fmaxf(acc2[pf][j] + bb, 0.f));
        }
    }
}

// ===========================================================================
// m97-style GEMM core + T2 source-swizzle (2D grid, x=bm y=bn).
// ===========================================================================
#define GEMM_CORE(Aptr, Bptr)                                                  \
    __shared__ s16x8 A8[1024];                                                 \
    __shared__ s16x8 B8[1024];                                                 \
    const int tid = threadIdx.x;                                               \
    const int l = tid & 63, w = tid >> 6;                                      \
    const int bm = blockIdx.x * 128;                                           \
    const int bn = blockIdx.y * 128;                                           \
    const int wr = w >> 1, wc = w & 1;                                         \
    const int srow = l >> 3;                                                   \
    const int scol = (((l & 7) ^ ((l >> 3) & 7)) * 8);                         \
    f32x4 acc[4][4];                                                           \
    _Pragma("unroll") for (int m = 0; m < 4; ++m)                              \
        _Pragma("unroll") for (int n = 0; n < 4; ++n) acc[m][n] = (f32x4)0.f;  \
    for (int kt = 0; kt < 8; ++kt) {                                           \
        __syncthreads();                                                       \
        _Pragma("unroll") for (int i = 0; i < 4; ++i) {                        \
            const int rb = w * 32 + i * 8;                                     \
            gl_lds(Aptr + (size_t)(bm + rb + srow) * 512 + kt * 64 + scol,     \
                   (char*)A8 + rb * 128);                                      \
            gl_lds(Bptr + (size_t)(bn + rb + srow) * 512 + kt * 64 + scol,     \
                   (char*)B8 + rb * 128);                                      \
        }                                                                      \
        __syncthreads();                                                       \
        _Pragma("unroll") for (int K32 = 0; K32 < 2; ++K32) {                  \
            const int kb = (K32 * 64 + (l >> 4) * 16) ^ ((l & 7) << 4);        \
            s16x8 a[4], b[4];                                                  \
            _Pragma("unroll") for (int m = 0; m < 4; ++m)                      \
                a[m] = A8[((wr * 64 + m * 16 + (l & 15)) * 128 + kb) >> 4];    \
            _Pragma("unroll") for (int n = 0; n < 4; ++n)                      \
                b[n] = B8[((wc * 64 + n * 16 + (l & 15)) * 128 + kb) >> 4];    \
            _Pragma("unroll") for (int m = 0; m < 4; ++m)                      \
                _Pragma("unroll") for (int n = 0; n < 4; ++n)                  \
                    acc[m][n] = __builtin_amdgcn_mfma_f32_16x16x32_bf16(       \
                        a[m], b[n], acc[m][n], 0, 0, 0);                       \
        }                                                                      \
    }

// ---------------------------------------------------------------------------
// K3 (GEMM): mu/var + reparameterize + KL.  grid (256, 8). eps NT-loaded.
// ---------------------------------------------------------------------------
__global__ __launch_bounds__(256, 4) void k_mv(const unsigned short* __restrict__ h2b,
                                               const unsigned short* __restrict__ wmv16,
                                               const float* __restrict__ bmu,
                                               const float* __restrict__ bvar,
                                               const float* __restrict__ eps,
                                               unsigned short* __restrict__ lat16,
                                               float* __restrict__ div_acc) {
    GEMM_CORE(h2b, wmv16)
    __shared__ float red[4];
    float kl = 0.f;
    const int dbase0 = (bn >> 1) + wc * 32;
#pragma unroll
    for (int m = 0; m < 4; ++m)
#pragma unroll
        for (int nn = 0; nn < 2; ++nn) {
            const int d = dbase0 + nn * 16 + (l & 15);
            const float bmv = bmu[d], bvv = bvar[d];
#pragma unroll
            for (int j = 0; j < 4; ++j) {
                const int r = bm + wr * 64 + m * 16 + (l >> 4) * 4 + j;
                float mu = acc[m][2 * nn][j] + bmv;
                float lv = acc[m][2 * nn + 1][j] + bvv;
                float ev = __builtin_nontemporal_load(&eps[(size_t)r * D_DIM + d]);
                float la = fmaf(ev, __expf(0.5f * lv), mu);
                lat16[(size_t)r * D_DIM + d] = f2bf(la);
                kl += mu * mu + __expf(lv) - lv - 1.f;
            }
        }
    kl *= 0.5f;
#pragma unroll
    for (int d = 1; d < 64; d <<= 1) kl += __shfl_xor(kl, d);
    if (l == 0) red[w] = kl;
    __syncthreads();
    if (tid == 0) atomicAdd(div_acc, red[0] + red[1] + red[2] + red[3]);
}

// ---------------------------------------------------------------------------
// K4 (GEMM sweep0): grid (256, 16). Per-row sumexp + packed-key argmax,
// LDS-precombined; exp(g) stored bf16 via NONTEMPORAL stores.
// ---------------------------------------------------------------------------
__global__ __launch_bounds__(256, 4) void k_vq1(const unsigned short* __restrict__ lat16,
                                                const unsigned short* __restrict__ pb16,
                                                const float* __restrict__ pnorm,
                                                float* __restrict__ rowS,
                                                unsigned* __restrict__ rowKey,
                                                unsigned short* __restrict__ gA,
                                                unsigned short* __restrict__ gB) {
    GEMM_CORE(lat16, pb16)
    __shared__ float rowS_l[128];
    __shared__ unsigned rowKey_l[128];
    if (tid < 128) { rowS_l[tid] = 0.f; rowKey_l[tid] = 0u; }
    __syncthreads();
    float pn[4];
#pragma unroll
    for (int n = 0; n < 4; ++n) pn[n] = pnorm[bn + wc * 64 + n * 16 + (l & 15)];
    s16x8* gd8 = (s16x8*)((blockIdx.y < 8) ? gA : gB);
    const size_t gbase = ((size_t)((blockIdx.y & 7) * 256 + blockIdx.x) * 8) * 256;
#pragma unroll
    for (int m = 0; m < 4; ++m) {
        float gv[4][4], ev[4][4];
#pragma unroll
        for (int n = 0; n < 4; ++n)
#pragma unroll
            for (int j = 0; j < 4; ++j) {
                gv[n][j] = 2.f * acc[m][n][j] - pn[n];
                ev[n][j] = __expf(gv[n][j]);
            }
        s16x8 u0, u1;
#pragma unroll
        for (int j = 0; j < 4; ++j) {
            u0[j] = (short)f2bf(ev[0][j]); u0[4 + j] = (short)f2bf(ev[1][j]);
            u1[j] = (short)f2bf(ev[2][j]); u1[4 + j] = (short)f2bf(ev[3][j]);
        }
        __builtin_nontemporal_store(u0, &gd8[gbase + (size_t)(m * 2 + 0) * 256 + tid]);
        __builtin_nontemporal_store(u1, &gd8[gbase + (size_t)(m * 2 + 1) * 256 + tid]);
#pragma unroll
        for (int j = 0; j < 4; ++j) {
            float se = ev[0][j] + ev[1][j] + ev[2][j] + ev[3][j];
            unsigned key = 0u;
#pragma unroll
            for (int n = 0; n < 4; ++n) {
                const int p = bn + wc * 64 + n * 16 + (l & 15);
                unsigned kk = (__float_as_uint(gv[n][j] + 16.0f) & 0xFFFFF800u) | (unsigned)(2047 - p);
                key = key > kk ? key : kk;
            }
#pragma unroll
            for (int d = 1; d < 16; d <<= 1) {
                se += __shfl_xor(se, d);
                unsigned ok = (unsigned)__shfl_xor((int)key, d);
                key = key > ok ? key : ok;
            }
            if ((l & 15) == 0) {
                const int rloc = wr * 64 + m * 16 + (l >> 4) * 4 + j;
                atomicAdd(&rowS_l[rloc], se);
                atomicMax(&rowKey_l[rloc], key);
            }
        }
    }
    __syncthreads();
    if (tid < 128) {
        atomicAdd(&rowS[bm + tid], rowS_l[tid]);
        atomicMax(&rowKey[bm + tid], rowKey_l[tid]);
    }
}

// ---------------------------------------------------------------------------
// K5 (streaming): soft_acc[p] += sum_rows exp(g)/rowS[row]; NT loads.
// ---------------------------------------------------------------------------
__global__ __launch_bounds__(256, 4) void k_vq2s(const unsigned short* __restrict__ gA,
                                                 const unsigned short* __restrict__ gB,
                                                 const float* __restrict__ rowS,
                                                 float* __restrict__ soft_acc) {
    __shared__ float soft_l[128];
    const int tid = threadIdx.x;
    const int l = tid & 63, w = tid >> 6;
    const int wr = w >> 1, wc = w & 1;
    const int bm = blockIdx.x * 128;
    const int bn = blockIdx.y * 128;
    if (tid < 128) soft_l[tid] = 0.f;
    __syncthreads();

    const s16x8* gs8 = (const s16x8*)((blockIdx.y < 8) ? gA : gB);
    const size_t gbase = ((size_t)((blockIdx.y & 7) * 256 + blockIdx.x) * 8) * 256;

    float is[4][4];
#pragma unroll
    for (int m = 0; m < 4; ++m)
#pragma unroll
        for (int j = 0; j < 4; ++j)
            is[m][j] = 1.0f / rowS[bm + wr * 64 + m * 16 + (l >> 4) * 4 + j];

    float cs[4] = {0.f, 0.f, 0.f, 0.f};
#pragma unroll
    for (int m = 0; m < 4; ++m) {
        s16x8 u0 = __builtin_nontemporal_load(&gs8[gbase + (size_t)(m * 2 + 0) * 256 + tid]);
        s16x8 u1 = __builtin_nontemporal_load(&gs8[gbase + (size_t)(m * 2 + 1) * 256 + tid]);
#pragma unroll
        for (int j = 0; j < 4; ++j) {
            cs[0] += bf2f((unsigned short)u0[j]) * is[m][j];
            cs[1] += bf2f((unsigned short)u0[4 + j]) * is[m][j];
            cs[2] += bf2f((unsigned short)u1[j]) * is[m][j];
            cs[3] += bf2f((unsigned short)u1[4 + j]) * is[m][j];
        }
    }
#pragma unroll
    for (int n = 0; n < 4; ++n) {
        cs[n] += __shfl_xor(cs[n], 16);
        cs[n] += __shfl_xor(cs[n], 32);
    }
    if (l < 16) {
#pragma unroll
        for (int n = 0; n < 4; ++n) atomicAdd(&soft_l[wc * 64 + n * 16 + l], cs[n]);
    }
    __syncthreads();
    if (tid < 128) atomicAdd(&soft_acc[bn + tid], soft_l[tid]);
}

// ---------------------------------------------------------------------------
// K6: out[r,:] = protos[idx[r],:] + vq partials (reads lat16; no atomics).
// ---------------------------------------------------------------------------
__global__ __launch_bounds__(256) void k_quant(const float* __restrict__ protos,
                                               const unsigned* __restrict__ rowKey,
                                               const unsigned short* __restrict__ lat16,
                                               float* __restrict__ out,
                                               float* __restrict__ vq_part) {
    const int tid = threadIdx.x;
    const int l = tid & 63, wid = tid >> 6;
    const int base = blockIdx.x * 64;
    float s = 0.f;
#pragma unroll
    for (int it = 0; it < 16; ++it) {
        const int r = base + it * 4 + wid;
        const int p = 2047 - (int)(rowKey[r] & 2047u);
        const float4* qp = (const float4*)(protos + (size_t)p * D_DIM);
        float4* op = (float4*)(out + (size_t)r * D_DIM);
        s16x8 lv = ((const s16x8*)(lat16 + (size_t)r * D_DIM))[l];
        float4 q1 = qp[l * 2], q2 = qp[l * 2 + 1];
        float d0 = q1.x - bf2f((unsigned short)lv[0]);
        float d1 = q1.y - bf2f((unsigned short)lv[1]);
        float d2 = q1.z - bf2f((unsigned short)lv[2]);
        float d3 = q1.w - bf2f((unsigned short)lv[3]);
        float d4 = q2.x - bf2f((unsigned short)lv[4]);
        float d5 = q2.y - bf2f((unsigned short)lv[5]);
        float d6 = q2.z - bf2f((unsigned short)lv[6]);
        float d7 = q2.w - bf2f((unsigned short)lv[7]);
        s += d0 * d0 + d1 * d1 + d2 * d2 + d3 * d3 +
             d4 * d4 + d5 * d5 + d6 * d6 + d7 * d7;
        op[l * 2] = q1; op[l * 2 + 1] = q2;
    }
#pragma unroll
    for (int m = 1; m < 64; m <<= 1) s += __shfl_xor(s, m);
    __shared__ float red[4];
    if (l == 0) red[wid] = s;
    __syncthreads();
    if (tid == 0) vq_part[blockIdx.x] = red[0] + red[1] + red[2] + red[3];
}

// ---------------------------------------------------------------------------
// K7: finalize scalars.
// ---------------------------------------------------------------------------
__global__ __launch_bounds__(256) void k_final(const float* __restrict__ soft_acc,
                                               const float* __restrict__ scal,
                                               const float* __restrict__ vq_part,
                                               float* __restrict__ out) {
    const int tid = threadIdx.x;
    __shared__ float red[256];
    float vals[8];
    float s = 0.f;
#pragma unroll
    for (int i = 0; i < 8; ++i) {
        float v = soft_acc[tid * 8 + i] * (1.0f / B_N) + 1e-6f;
        vals[i] = v;
        s += v;
    }
    red[tid] = s;
    __syncthreads();
    for (int off = 128; off > 0; off >>= 1) {
        if (tid < off) red[tid] += red[tid + off];
        __syncthreads();
    }
    float norm = red[0];
    __syncthreads();
    float e = 0.f;
#pragma unroll
    for (int i = 0; i < 8; ++i) {
        float p = vals[i] / norm;
        e -= p * __logf(p);
    }
    red[tid] = e;
    __syncthreads();
    for (int off = 128; off > 0; off >>= 1) {
        if (tid < off) red[tid] += red[tid + off];
        __syncthreads();
    }
    float ent = red[0];
    __syncthreads();
    red[tid] = vq_part[tid] + vq_part[tid + 256];
    __syncthreads();
    for (int off = 128; off > 0; off >>= 1) {
        if (tid < off) red[tid] += red[tid + off];
        __syncthreads();
    }
    if (tid == 0) {
        float div = scal[0] * (1.0f / B_N);
        float vq = red[0] * (1.0f / ((float)B_N * (float)D_DIM));
        float vq_loss = 1.25f * vq + 0.1f * ent;
        float total = 0.01f * div + vq_loss;
        out[(size_t)B_N * D_DIM] = total;
        out[(size_t)B_N * D_DIM + 1] = div;
    }
}

// ---------------------------------------------------------------------------
extern "C" void kernel_launch(void* const* d_in, const int* in_sizes, int n_in,
                              void* d_out, int out_size, void* d_ws, size_t ws_size,
                              hipStream_t stream) {
    const float* x = (const float*)d_in[0];
    const float* W0 = (const float*)d_in[1];
    const float* b0 = (const float*)d_in[2];
    const float* W1 = (const float*)d_in[3];
    const float* b1 = (const float*)d_in[4];
    const float* Wmu = (const float*)d_in[5];
    const float* bmu = (const float*)d_in[6];
    const float* Wvar = (const float*)d_in[7];
    const float* bvar = (const float*)d_in[8];
    const float* protos = (const float*)d_in[9];
    const float* eps = (const float*)d_in[10];
    float* out = (float*)d_out;

    unsigned short* wsp = (unsigned short*)d_ws;
    unsigned short* lat16 = wsp;                                 // 32MB
    unsigned short* pb16 = lat16 + (size_t)B_N * D_DIM;          // 2MB
    unsigned short* wmv16 = pb16 + (size_t)P_N * D_DIM;          // 2MB
    unsigned short* w0pack = wmv16 + (size_t)2 * D_DIM * D_DIM;  // 128KB
    unsigned short* w1pack = w0pack + (size_t)HID * IN_DIM;      // 64KB
    float* pnorm = (float*)(w1pack + (size_t)D_DIM * HID);       // 8KB
    float* rowS = pnorm + P_N;                                   // 128KB
    unsigned* rowKey = (unsigned*)(rowS + B_N);                  // 128KB
    float* soft = (float*)(rowKey + B_N);                        // 8KB
    float* scal = soft + P_N;                                    // 8B
    float* vqpart = scal + 2;                                    // 2KB
    unsigned short* h2b = (unsigned short*)(vqpart + 512) +
                          (size_t)B_N * HID;                     // 32MB (inside gA region)
    unsigned short* gA = (unsigned short*)(vqpart + 512);        // 64MB alias (live after k_mv)
    unsigned short* gB = (unsigned short*)d_out;                 // 64MB (live until k_quant)

    hipMemsetAsync(rowS, 0, (size_t)(B_N * 2 + P_N + 2) * 4, stream);

    k_prep<<<816, 256, 0, stream>>>(protos, Wmu, Wvar, W0, W1,
                                    pb16, pnorm, wmv16, w0pack, w1pack);

    k_enc<<<B_N / 64, 256, 0, stream>>>(x, w0pack, b0, w1pack, b1, h2b);

    dim3 gmv(B_N / 128, 8);
    k_mv<<<gmv, 256, 0, stream>>>(h2b, wmv16, bmu, bvar, eps, lat16, scal);

    dim3 gvq(B_N / 128, 16);
    k_vq1<<<gvq, 256, 0, stream>>>(lat16, pb16, pnorm, rowS, rowKey, gA, gB);
    k_vq2s<<<gvq, 256, 0, stream>>>(gA, gB, rowS, soft);

    k_quant<<<B_N / 64, 256, 0, stream>>>(protos, rowKey, lat16, out, vqpart);
    k_final<<<1, 256, 0, stream>>>(soft, scal, vqpart, out);
}